// Round 1
// baseline (11536.935 us; speedup 1.0000x reference)
//
#include <hip/hip_runtime.h>

#define F_IN 256
#define EDIM 128
#define ALPHA 0.2f

// Transpose cat_W [128][256] -> Wt [256][128] so GEMM2 reads are coalesced.
__global__ void k_transpose_catW(const float* __restrict__ catW, float* __restrict__ Wt) {
    int idx = blockIdx.x * 256 + threadIdx.x;
    if (idx < EDIM * 2 * EDIM) {
        int r = idx >> 8;      // row in catW (0..127)
        int c = idx & 255;     // col in catW (0..255)
        Wt[c * EDIM + r] = catW[idx];
    }
}

// support = relu(feature @ W)   feature[N][256], W[256][128]
// block = 128 threads, 4 rows per block; each 32-thread group does one row,
// each thread computes 4 contiguous output columns (float4 of W per k).
__global__ void k_gemm1_relu(const float* __restrict__ feature, const float* __restrict__ W,
                             float* __restrict__ support, int n) {
    int t = threadIdx.x;
    int row = blockIdx.x * 4 + (t >> 5);
    if (row >= n) return;
    int c = (t & 31) * 4;
    const float* frow = feature + (size_t)row * F_IN;
    float4 acc = make_float4(0.f, 0.f, 0.f, 0.f);
    for (int k = 0; k < F_IN; ++k) {
        float f = frow[k];
        const float4 w = *reinterpret_cast<const float4*>(W + k * EDIM + c);
        acc.x = fmaf(f, w.x, acc.x);
        acc.y = fmaf(f, w.y, acc.y);
        acc.z = fmaf(f, w.z, acc.z);
        acc.w = fmaf(f, w.w, acc.w);
    }
    float4 r;
    r.x = fmaxf(acc.x, 0.f); r.y = fmaxf(acc.y, 0.f);
    r.z = fmaxf(acc.z, 0.f); r.w = fmaxf(acc.w, 0.f);
    *reinterpret_cast<float4*>(support + (size_t)row * EDIM + c) = r;
}

// y[row[e]] += val[e] * x[col[e]]  — 32 threads per edge, float4 per thread.
__global__ void k_spmm_atomic(const int* __restrict__ erow, const int* __restrict__ ecol,
                              const float* __restrict__ eval, const float* __restrict__ x,
                              float* __restrict__ y, int nE) {
    long long gid = (long long)blockIdx.x * blockDim.x + threadIdx.x;
    int e = (int)(gid >> 5);
    if (e >= nE) return;
    int c = ((int)gid & 31) * 4;
    int r = erow[e];
    int s = ecol[e];
    float v = eval[e];
    const float4 xv = *reinterpret_cast<const float4*>(x + (size_t)s * EDIM + c);
    float* yp = y + (size_t)r * EDIM + c;
    atomicAdd(yp + 0, v * xv.x);
    atomicAdd(yp + 1, v * xv.y);
    atomicAdd(yp + 2, v * xv.z);
    atomicAdd(yp + 3, v * xv.w);
}

// out = leaky_relu([s1+sup, s2-sup] @ Wt + cat_b) + b
// s2 lives in `out`; each block reads its rows fully before overwriting them.
__global__ void k_final(const float* __restrict__ support, const float* __restrict__ s1,
                        float* __restrict__ out, const float* __restrict__ Wt,
                        const float* __restrict__ catb, const float* __restrict__ bvec, int n) {
    __shared__ float cat[4][2 * EDIM];
    int t = threadIdx.x;
    int rg = t >> 5;
    int c = (t & 31) * 4;
    int row = blockIdx.x * 4 + rg;
    if (row < n) {
        size_t off = (size_t)row * EDIM + c;
        float4 sup = *reinterpret_cast<const float4*>(support + off);
        float4 a = *reinterpret_cast<const float4*>(s1 + off);
        float4 m = *reinterpret_cast<const float4*>(out + off);  // s2
        cat[rg][c + 0] = a.x + sup.x;  cat[rg][c + 1] = a.y + sup.y;
        cat[rg][c + 2] = a.z + sup.z;  cat[rg][c + 3] = a.w + sup.w;
        cat[rg][EDIM + c + 0] = m.x - sup.x;  cat[rg][EDIM + c + 1] = m.y - sup.y;
        cat[rg][EDIM + c + 2] = m.z - sup.z;  cat[rg][EDIM + c + 3] = m.w - sup.w;
    }
    __syncthreads();
    if (row >= n) return;
    float4 acc = make_float4(0.f, 0.f, 0.f, 0.f);
    for (int k = 0; k < 2 * EDIM; ++k) {
        float f = cat[rg][k];
        const float4 w = *reinterpret_cast<const float4*>(Wt + k * EDIM + c);
        acc.x = fmaf(f, w.x, acc.x);
        acc.y = fmaf(f, w.y, acc.y);
        acc.z = fmaf(f, w.z, acc.z);
        acc.w = fmaf(f, w.w, acc.w);
    }
    const float4 cb = *reinterpret_cast<const float4*>(catb + c);
    const float4 bb = *reinterpret_cast<const float4*>(bvec + c);
    acc.x += cb.x; acc.y += cb.y; acc.z += cb.z; acc.w += cb.w;
    float4 r;
    r.x = (acc.x > 0.f ? acc.x : ALPHA * acc.x) + bb.x;
    r.y = (acc.y > 0.f ? acc.y : ALPHA * acc.y) + bb.y;
    r.z = (acc.z > 0.f ? acc.z : ALPHA * acc.z) + bb.z;
    r.w = (acc.w > 0.f ? acc.w : ALPHA * acc.w) + bb.w;
    *reinterpret_cast<float4*>(out + (size_t)row * EDIM + c) = r;
}

extern "C" void kernel_launch(void* const* d_in, const int* in_sizes, int n_in,
                              void* d_out, int out_size, void* d_ws, size_t ws_size,
                              hipStream_t stream) {
    const float* feature = (const float*)d_in[0];
    const int*   erow    = (const int*)d_in[1];
    const int*   ecol    = (const int*)d_in[2];
    const float* eval    = (const float*)d_in[3];
    const float* W       = (const float*)d_in[4];
    const float* b       = (const float*)d_in[5];
    const float* catW    = (const float*)d_in[6];
    const float* catb    = (const float*)d_in[7];
    float* out = (float*)d_out;

    const int n  = in_sizes[0] / F_IN;
    const int nE = in_sizes[1];

    float* support = (float*)d_ws;                       // n*128 f32
    float* s1      = support + (size_t)n * EDIM;         // n*128 f32
    float* Wt      = s1 + (size_t)n * EDIM;              // 256*128 f32

    // Wt = cat_W.T
    k_transpose_catW<<<(EDIM * 2 * EDIM + 255) / 256, 256, 0, stream>>>(catW, Wt);

    // support = relu(feature @ W)
    const int rowBlocks = (n + 3) / 4;
    k_gemm1_relu<<<rowBlocks, 128, 0, stream>>>(feature, W, support, n);

    // s1 = spmm(support)
    hipMemsetAsync(s1, 0, (size_t)n * EDIM * sizeof(float), stream);
    const long long tot = (long long)nE * 32;
    const int eBlocks = (int)((tot + 255) / 256);
    k_spmm_atomic<<<eBlocks, 256, 0, stream>>>(erow, ecol, eval, support, s1, nE);

    // s2 = spmm(s1), accumulated directly in d_out
    hipMemsetAsync(out, 0, (size_t)n * EDIM * sizeof(float), stream);
    k_spmm_atomic<<<eBlocks, 256, 0, stream>>>(erow, ecol, eval, s1, out, nE);

    // out = leaky_relu([s1+sup, s2-sup] @ Wt + cat_b) + b
    k_final<<<rowBlocks, 128, 0, stream>>>(support, s1, out, Wt, catb, b, n);
}

// Round 2
// 1635.830 us; speedup vs baseline: 7.0526x; 7.0526x over previous
//
#include <hip/hip_runtime.h>

#define F_IN 256
#define EDIM 128
#define ALPHA 0.2f
#define SCAN_B 1024

// ---------------- CSR build ----------------

__global__ void k_hist(const int* __restrict__ erow, int* __restrict__ cnt, int nE) {
    int e = blockIdx.x * 256 + threadIdx.x;
    if (e < nE) atomicAdd(&cnt[erow[e]], 1);
}

// Per-block exclusive scan of cnt -> rp (block-local), block totals -> bsum.
__global__ void k_scan_block(const int* __restrict__ cnt, int* __restrict__ rp,
                             int* __restrict__ bsum, int n) {
    __shared__ int s[SCAN_B];
    int t = threadIdx.x;
    int i = blockIdx.x * SCAN_B + t;
    int v = (i < n) ? cnt[i] : 0;
    s[t] = v;
    __syncthreads();
    for (int d = 1; d < SCAN_B; d <<= 1) {
        int add = (t >= d) ? s[t - d] : 0;
        __syncthreads();
        s[t] += add;
        __syncthreads();
    }
    if (i < n) rp[i] = s[t] - v;       // exclusive within block
    if (t == SCAN_B - 1) bsum[blockIdx.x] = s[t];
}

// Scan the (<=1024) block sums; boff = exclusive, boff[nb] = total.
__global__ void k_scan_bsums(const int* __restrict__ bsum, int* __restrict__ boff, int nb) {
    __shared__ int s[SCAN_B];
    int t = threadIdx.x;
    int v = (t < nb) ? bsum[t] : 0;
    s[t] = v;
    __syncthreads();
    for (int d = 1; d < SCAN_B; d <<= 1) {
        int add = (t >= d) ? s[t - d] : 0;
        __syncthreads();
        s[t] += add;
        __syncthreads();
    }
    if (t < nb) boff[t] = s[t] - v;
    if (t == SCAN_B - 1) boff[nb] = s[t];
}

// rp[i] += boff[block]; cur[i] = rp[i]; rp[n] = total.
__global__ void k_add_off(int* __restrict__ rp, int* __restrict__ cur,
                          const int* __restrict__ boff, int n, int nb) {
    int i = blockIdx.x * SCAN_B + threadIdx.x;
    if (i < n) {
        int v = rp[i] + boff[blockIdx.x];
        rp[i] = v;
        cur[i] = v;
    }
    if (i == n) rp[n] = boff[nb];
}

__global__ void k_scatter(const int* __restrict__ erow, const int* __restrict__ ecol,
                          const float* __restrict__ eval, int* __restrict__ cur,
                          int2* __restrict__ edges, int nE) {
    int e = blockIdx.x * 256 + threadIdx.x;
    if (e >= nE) return;
    int pos = atomicAdd(&cur[erow[e]], 1);
    edges[pos] = make_int2(ecol[e], __float_as_int(eval[e]));
}

// ---------------- compute ----------------

__global__ void k_transpose_catW(const float* __restrict__ catW, float* __restrict__ Wt) {
    int idx = blockIdx.x * 256 + threadIdx.x;
    if (idx < EDIM * 2 * EDIM) {
        int r = idx >> 8;
        int c = idx & 255;
        Wt[c * EDIM + r] = catW[idx];
    }
}

__global__ void k_gemm1_relu(const float* __restrict__ feature, const float* __restrict__ W,
                             float* __restrict__ support, int n) {
    int t = threadIdx.x;
    int row = blockIdx.x * 4 + (t >> 5);
    if (row >= n) return;
    int c = (t & 31) * 4;
    const float* frow = feature + (size_t)row * F_IN;
    float4 acc = make_float4(0.f, 0.f, 0.f, 0.f);
    for (int k = 0; k < F_IN; ++k) {
        float f = frow[k];
        const float4 w = *reinterpret_cast<const float4*>(W + k * EDIM + c);
        acc.x = fmaf(f, w.x, acc.x);
        acc.y = fmaf(f, w.y, acc.y);
        acc.z = fmaf(f, w.z, acc.z);
        acc.w = fmaf(f, w.w, acc.w);
    }
    float4 r;
    r.x = fmaxf(acc.x, 0.f); r.y = fmaxf(acc.y, 0.f);
    r.z = fmaxf(acc.z, 0.f); r.w = fmaxf(acc.w, 0.f);
    *reinterpret_cast<float4*>(support + (size_t)row * EDIM + c) = r;
}

// One wave per destination row; lane holds float2 of the 128 output cols.
__global__ void k_spmm_csr(const int* __restrict__ rowptr, const int2* __restrict__ edges,
                           const float* __restrict__ x, float* __restrict__ y, int n) {
    int wid = threadIdx.x >> 6;
    int lane = threadIdx.x & 63;
    int row = blockIdx.x * 4 + wid;
    if (row >= n) return;
    int beg = rowptr[row];
    int end = rowptr[row + 1];
    int c = lane * 2;
    float ax = 0.f, ay = 0.f;
    int j = beg;
    for (; j + 4 <= end; j += 4) {
        int2 e0 = edges[j];
        int2 e1 = edges[j + 1];
        int2 e2 = edges[j + 2];
        int2 e3 = edges[j + 3];
        const float2 x0 = *reinterpret_cast<const float2*>(x + (size_t)e0.x * EDIM + c);
        const float2 x1 = *reinterpret_cast<const float2*>(x + (size_t)e1.x * EDIM + c);
        const float2 x2 = *reinterpret_cast<const float2*>(x + (size_t)e2.x * EDIM + c);
        const float2 x3 = *reinterpret_cast<const float2*>(x + (size_t)e3.x * EDIM + c);
        ax = fmaf(__int_as_float(e0.y), x0.x, ax); ay = fmaf(__int_as_float(e0.y), x0.y, ay);
        ax = fmaf(__int_as_float(e1.y), x1.x, ax); ay = fmaf(__int_as_float(e1.y), x1.y, ay);
        ax = fmaf(__int_as_float(e2.y), x2.x, ax); ay = fmaf(__int_as_float(e2.y), x2.y, ay);
        ax = fmaf(__int_as_float(e3.y), x3.x, ax); ay = fmaf(__int_as_float(e3.y), x3.y, ay);
    }
    for (; j < end; ++j) {
        int2 e = edges[j];
        const float2 xv = *reinterpret_cast<const float2*>(x + (size_t)e.x * EDIM + c);
        ax = fmaf(__int_as_float(e.y), xv.x, ax);
        ay = fmaf(__int_as_float(e.y), xv.y, ay);
    }
    *reinterpret_cast<float2*>(y + (size_t)row * EDIM + c) = make_float2(ax, ay);
}

__global__ void k_final(const float* __restrict__ support, const float* __restrict__ s1,
                        float* __restrict__ out, const float* __restrict__ Wt,
                        const float* __restrict__ catb, const float* __restrict__ bvec, int n) {
    __shared__ float cat[4][2 * EDIM];
    int t = threadIdx.x;
    int rg = t >> 5;
    int c = (t & 31) * 4;
    int row = blockIdx.x * 4 + rg;
    if (row < n) {
        size_t off = (size_t)row * EDIM + c;
        float4 sup = *reinterpret_cast<const float4*>(support + off);
        float4 a = *reinterpret_cast<const float4*>(s1 + off);
        float4 m = *reinterpret_cast<const float4*>(out + off);  // s2
        cat[rg][c + 0] = a.x + sup.x;  cat[rg][c + 1] = a.y + sup.y;
        cat[rg][c + 2] = a.z + sup.z;  cat[rg][c + 3] = a.w + sup.w;
        cat[rg][EDIM + c + 0] = m.x - sup.x;  cat[rg][EDIM + c + 1] = m.y - sup.y;
        cat[rg][EDIM + c + 2] = m.z - sup.z;  cat[rg][EDIM + c + 3] = m.w - sup.w;
    }
    __syncthreads();
    if (row >= n) return;
    float4 acc = make_float4(0.f, 0.f, 0.f, 0.f);
    for (int k = 0; k < 2 * EDIM; ++k) {
        float f = cat[rg][k];
        const float4 w = *reinterpret_cast<const float4*>(Wt + k * EDIM + c);
        acc.x = fmaf(f, w.x, acc.x);
        acc.y = fmaf(f, w.y, acc.y);
        acc.z = fmaf(f, w.z, acc.z);
        acc.w = fmaf(f, w.w, acc.w);
    }
    const float4 cb = *reinterpret_cast<const float4*>(catb + c);
    const float4 bb = *reinterpret_cast<const float4*>(bvec + c);
    acc.x += cb.x; acc.y += cb.y; acc.z += cb.z; acc.w += cb.w;
    float4 r;
    r.x = (acc.x > 0.f ? acc.x : ALPHA * acc.x) + bb.x;
    r.y = (acc.y > 0.f ? acc.y : ALPHA * acc.y) + bb.y;
    r.z = (acc.z > 0.f ? acc.z : ALPHA * acc.z) + bb.z;
    r.w = (acc.w > 0.f ? acc.w : ALPHA * acc.w) + bb.w;
    *reinterpret_cast<float4*>(out + (size_t)row * EDIM + c) = r;
}

extern "C" void kernel_launch(void* const* d_in, const int* in_sizes, int n_in,
                              void* d_out, int out_size, void* d_ws, size_t ws_size,
                              hipStream_t stream) {
    const float* feature = (const float*)d_in[0];
    const int*   erow    = (const int*)d_in[1];
    const int*   ecol    = (const int*)d_in[2];
    const float* eval    = (const float*)d_in[3];
    const float* W       = (const float*)d_in[4];
    const float* b       = (const float*)d_in[5];
    const float* catW    = (const float*)d_in[6];
    const float* catb    = (const float*)d_in[7];
    float* out = (float*)d_out;

    const int n  = in_sizes[0] / F_IN;
    const int nE = in_sizes[1];
    const int nb = (n + SCAN_B - 1) / SCAN_B;   // <= 1024 assumed (n <= 1M)

    // workspace layout (8-byte aligned chunks)
    char* p = (char*)d_ws;
    float* support = (float*)p;             p += (size_t)n * EDIM * sizeof(float);
    float* s1      = (float*)p;             p += (size_t)n * EDIM * sizeof(float);
    float* Wt      = (float*)p;             p += (size_t)F_IN * EDIM * sizeof(float);
    int2*  edges   = (int2*)p;              p += (size_t)nE * sizeof(int2);
    int*   cnt     = (int*)p;               p += (size_t)n * sizeof(int);
    int*   rowptr  = (int*)p;               p += (size_t)(n + 1) * sizeof(int);
    int*   cur     = (int*)p;               p += (size_t)n * sizeof(int);
    int*   bsum    = (int*)p;               p += (size_t)nb * sizeof(int);
    int*   boff    = (int*)p;               p += (size_t)(nb + 1) * sizeof(int);

    const int eB = (nE + 255) / 256;
    const int rowBlocks = (n + 3) / 4;

    // ---- CSR build (counting sort by destination row) ----
    hipMemsetAsync(cnt, 0, (size_t)n * sizeof(int), stream);
    k_hist<<<eB, 256, 0, stream>>>(erow, cnt, nE);
    k_scan_block<<<nb, SCAN_B, 0, stream>>>(cnt, rowptr, bsum, n);
    k_scan_bsums<<<1, SCAN_B, 0, stream>>>(bsum, boff, nb);
    k_add_off<<<nb, SCAN_B, 0, stream>>>(rowptr, cur, boff, n, nb);
    k_scatter<<<eB, 256, 0, stream>>>(erow, ecol, eval, cur, edges, nE);

    // ---- dense prologue ----
    k_transpose_catW<<<(EDIM * 2 * EDIM + 255) / 256, 256, 0, stream>>>(catW, Wt);
    k_gemm1_relu<<<rowBlocks, 128, 0, stream>>>(feature, W, support, n);

    // ---- SpMMs (gather, no atomics) ----
    k_spmm_csr<<<rowBlocks, 256, 0, stream>>>(rowptr, edges, support, s1, n);
    k_spmm_csr<<<rowBlocks, 256, 0, stream>>>(rowptr, edges, s1, out, n);  // s2 -> out

    // ---- epilogue GEMM ----
    k_final<<<rowBlocks, 128, 0, stream>>>(support, s1, out, Wt, catb, b, n);
}

// Round 3
// 971.272 us; speedup vs baseline: 11.8782x; 1.6842x over previous
//
#include <hip/hip_runtime.h>

#define F_IN 256
#define EDIM 128
#define ALPHA 0.2f
#define SCAN_B 1024
#define BM 128
#define BK 16

// ---------------- CSR build ----------------

__global__ void k_hist(const int* __restrict__ erow, int* __restrict__ cnt, int nE) {
    int e = blockIdx.x * 256 + threadIdx.x;
    if (e < nE) atomicAdd(&cnt[erow[e]], 1);
}

__global__ void k_scan_block(const int* __restrict__ cnt, int* __restrict__ rp,
                             int* __restrict__ bsum, int n) {
    __shared__ int s[SCAN_B];
    int t = threadIdx.x;
    int i = blockIdx.x * SCAN_B + t;
    int v = (i < n) ? cnt[i] : 0;
    s[t] = v;
    __syncthreads();
    for (int d = 1; d < SCAN_B; d <<= 1) {
        int add = (t >= d) ? s[t - d] : 0;
        __syncthreads();
        s[t] += add;
        __syncthreads();
    }
    if (i < n) rp[i] = s[t] - v;
    if (t == SCAN_B - 1) bsum[blockIdx.x] = s[t];
}

__global__ void k_scan_bsums(const int* __restrict__ bsum, int* __restrict__ boff, int nb) {
    __shared__ int s[SCAN_B];
    int t = threadIdx.x;
    int v = (t < nb) ? bsum[t] : 0;
    s[t] = v;
    __syncthreads();
    for (int d = 1; d < SCAN_B; d <<= 1) {
        int add = (t >= d) ? s[t - d] : 0;
        __syncthreads();
        s[t] += add;
        __syncthreads();
    }
    if (t < nb) boff[t] = s[t] - v;
    if (t == SCAN_B - 1) boff[nb] = s[t];
}

__global__ void k_add_off(int* __restrict__ rp, int* __restrict__ cur,
                          const int* __restrict__ boff, int n, int nb) {
    int i = blockIdx.x * SCAN_B + threadIdx.x;
    if (i < n) {
        int v = rp[i] + boff[blockIdx.x];
        rp[i] = v;
        cur[i] = v;
    }
    if (i == n) rp[n] = boff[nb];
}

__global__ void k_scatter(const int* __restrict__ erow, const int* __restrict__ ecol,
                          const float* __restrict__ eval, int* __restrict__ cur,
                          int2* __restrict__ edges, int nE) {
    int e = blockIdx.x * 256 + threadIdx.x;
    if (e >= nE) return;
    int pos = atomicAdd(&cur[erow[e]], 1);
    edges[pos] = make_int2(ecol[e], __float_as_int(eval[e]));
}

// ---------------- dense ----------------

__global__ void k_transpose_catW(const float* __restrict__ catW, float* __restrict__ Wt) {
    int idx = blockIdx.x * 256 + threadIdx.x;
    if (idx < EDIM * 2 * EDIM) {
        int r = idx >> 8;
        int c = idx & 255;
        Wt[c * EDIM + r] = catW[idx];
    }
}

#define FMA_ROW(accv, a, bv) \
    accv.x = fmaf(a, bv.x, accv.x); accv.y = fmaf(a, bv.y, accv.y); \
    accv.z = fmaf(a, bv.z, accv.z); accv.w = fmaf(a, bv.w, accv.w);

// Tiled GEMM: C[128 rows][128 cols] per block, 256 threads, 8x8 micro-tile.
// thread t: tr=t>>4, tc=t&15; rows {r0+rh*64+tr*4+i}, cols {ch*64+tc*4+j}.
__global__ __launch_bounds__(256) void k_gemm1_relu(const float* __restrict__ feature,
                                                    const float* __restrict__ W,
                                                    float* __restrict__ support, int n) {
    __shared__ float As[BK][BM + 4];
    __shared__ float Bs[BK][EDIM];
    const int t = threadIdx.x;
    const int tr = t >> 4, tc = t & 15;
    const int r0 = blockIdx.x * BM;
    float4 acc[2][4][2];
    #pragma unroll
    for (int rh = 0; rh < 2; ++rh)
        #pragma unroll
        for (int i = 0; i < 4; ++i)
            #pragma unroll
            for (int ch = 0; ch < 2; ++ch)
                acc[rh][i][ch] = make_float4(0.f, 0.f, 0.f, 0.f);

    for (int kt = 0; kt < F_IN / BK; ++kt) {
        const int k0 = kt * BK;
        #pragma unroll
        for (int i = 0; i < 2; ++i) {          // A: 128x16 -> As[k][m] (transposed)
            int u = t * 2 + i;
            int r = u >> 2;
            int kc = (u & 3) * 4;
            float4 v = make_float4(0.f, 0.f, 0.f, 0.f);
            if (r0 + r < n)
                v = *reinterpret_cast<const float4*>(feature + (size_t)(r0 + r) * F_IN + k0 + kc);
            As[kc + 0][r] = v.x; As[kc + 1][r] = v.y;
            As[kc + 2][r] = v.z; As[kc + 3][r] = v.w;
        }
        #pragma unroll
        for (int i = 0; i < 2; ++i) {          // B: 16x128 (k-major already)
            int u = t * 2 + i;
            int kb = u >> 5;
            int cb = (u & 31) * 4;
            *reinterpret_cast<float4*>(&Bs[kb][cb]) =
                *reinterpret_cast<const float4*>(W + (size_t)(k0 + kb) * EDIM + cb);
        }
        __syncthreads();
        #pragma unroll
        for (int k = 0; k < BK; ++k) {
            float4 a0 = *reinterpret_cast<const float4*>(&As[k][tr * 4]);
            float4 a1 = *reinterpret_cast<const float4*>(&As[k][64 + tr * 4]);
            float4 b0 = *reinterpret_cast<const float4*>(&Bs[k][tc * 4]);
            float4 b1 = *reinterpret_cast<const float4*>(&Bs[k][64 + tc * 4]);
            FMA_ROW(acc[0][0][0], a0.x, b0) FMA_ROW(acc[0][0][1], a0.x, b1)
            FMA_ROW(acc[0][1][0], a0.y, b0) FMA_ROW(acc[0][1][1], a0.y, b1)
            FMA_ROW(acc[0][2][0], a0.z, b0) FMA_ROW(acc[0][2][1], a0.z, b1)
            FMA_ROW(acc[0][3][0], a0.w, b0) FMA_ROW(acc[0][3][1], a0.w, b1)
            FMA_ROW(acc[1][0][0], a1.x, b0) FMA_ROW(acc[1][0][1], a1.x, b1)
            FMA_ROW(acc[1][1][0], a1.y, b0) FMA_ROW(acc[1][1][1], a1.y, b1)
            FMA_ROW(acc[1][2][0], a1.z, b0) FMA_ROW(acc[1][2][1], a1.z, b1)
            FMA_ROW(acc[1][3][0], a1.w, b0) FMA_ROW(acc[1][3][1], a1.w, b1)
        }
        __syncthreads();
    }
    #pragma unroll
    for (int rh = 0; rh < 2; ++rh)
        #pragma unroll
        for (int i = 0; i < 4; ++i) {
            int row = r0 + rh * 64 + tr * 4 + i;
            if (row >= n) continue;
            float* dst = support + (size_t)row * EDIM;
            float4 v0 = acc[rh][i][0], v1 = acc[rh][i][1];
            v0.x = fmaxf(v0.x, 0.f); v0.y = fmaxf(v0.y, 0.f);
            v0.z = fmaxf(v0.z, 0.f); v0.w = fmaxf(v0.w, 0.f);
            v1.x = fmaxf(v1.x, 0.f); v1.y = fmaxf(v1.y, 0.f);
            v1.z = fmaxf(v1.z, 0.f); v1.w = fmaxf(v1.w, 0.f);
            *reinterpret_cast<float4*>(dst + tc * 4) = v0;
            *reinterpret_cast<float4*>(dst + 64 + tc * 4) = v1;
        }
}

// out = leaky_relu([s1+sup | s2-sup] @ Wt + catb) + b, s2 lives in `out`.
__global__ __launch_bounds__(256) void k_final(const float* __restrict__ support,
                                               const float* __restrict__ s1,
                                               float* __restrict__ out,
                                               const float* __restrict__ Wt,
                                               const float* __restrict__ catb,
                                               const float* __restrict__ bvec, int n) {
    __shared__ float As[BK][BM + 4];
    __shared__ float Bs[BK][EDIM];
    const int t = threadIdx.x;
    const int tr = t >> 4, tc = t & 15;
    const int r0 = blockIdx.x * BM;
    float4 acc[2][4][2];
    #pragma unroll
    for (int rh = 0; rh < 2; ++rh)
        #pragma unroll
        for (int i = 0; i < 4; ++i)
            #pragma unroll
            for (int ch = 0; ch < 2; ++ch)
                acc[rh][i][ch] = make_float4(0.f, 0.f, 0.f, 0.f);

    for (int kt = 0; kt < (2 * EDIM) / BK; ++kt) {
        const int k0 = kt * BK;
        #pragma unroll
        for (int i = 0; i < 2; ++i) {          // A: cat tile computed on the fly
            int u = t * 2 + i;
            int r = u >> 2;
            int kc = (u & 3) * 4;
            int kk = k0 + kc;
            float4 v = make_float4(0.f, 0.f, 0.f, 0.f);
            if (r0 + r < n) {
                if (kk < EDIM) {
                    size_t off = (size_t)(r0 + r) * EDIM + kk;
                    float4 p = *reinterpret_cast<const float4*>(s1 + off);
                    float4 q = *reinterpret_cast<const float4*>(support + off);
                    v = make_float4(p.x + q.x, p.y + q.y, p.z + q.z, p.w + q.w);
                } else {
                    size_t off = (size_t)(r0 + r) * EDIM + (kk - EDIM);
                    float4 p = *reinterpret_cast<const float4*>(out + off);   // s2
                    float4 q = *reinterpret_cast<const float4*>(support + off);
                    v = make_float4(p.x - q.x, p.y - q.y, p.z - q.z, p.w - q.w);
                }
            }
            As[kc + 0][r] = v.x; As[kc + 1][r] = v.y;
            As[kc + 2][r] = v.z; As[kc + 3][r] = v.w;
        }
        #pragma unroll
        for (int i = 0; i < 2; ++i) {
            int u = t * 2 + i;
            int kb = u >> 5;
            int cb = (u & 31) * 4;
            *reinterpret_cast<float4*>(&Bs[kb][cb]) =
                *reinterpret_cast<const float4*>(Wt + (size_t)(k0 + kb) * EDIM + cb);
        }
        __syncthreads();
        #pragma unroll
        for (int k = 0; k < BK; ++k) {
            float4 a0 = *reinterpret_cast<const float4*>(&As[k][tr * 4]);
            float4 a1 = *reinterpret_cast<const float4*>(&As[k][64 + tr * 4]);
            float4 b0 = *reinterpret_cast<const float4*>(&Bs[k][tc * 4]);
            float4 b1 = *reinterpret_cast<const float4*>(&Bs[k][64 + tc * 4]);
            FMA_ROW(acc[0][0][0], a0.x, b0) FMA_ROW(acc[0][0][1], a0.x, b1)
            FMA_ROW(acc[0][1][0], a0.y, b0) FMA_ROW(acc[0][1][1], a0.y, b1)
            FMA_ROW(acc[0][2][0], a0.z, b0) FMA_ROW(acc[0][2][1], a0.z, b1)
            FMA_ROW(acc[0][3][0], a0.w, b0) FMA_ROW(acc[0][3][1], a0.w, b1)
            FMA_ROW(acc[1][0][0], a1.x, b0) FMA_ROW(acc[1][0][1], a1.x, b1)
            FMA_ROW(acc[1][1][0], a1.y, b0) FMA_ROW(acc[1][1][1], a1.y, b1)
            FMA_ROW(acc[1][2][0], a1.z, b0) FMA_ROW(acc[1][2][1], a1.z, b1)
            FMA_ROW(acc[1][3][0], a1.w, b0) FMA_ROW(acc[1][3][1], a1.w, b1)
        }
        __syncthreads();
    }
    const float4 cb0 = *reinterpret_cast<const float4*>(catb + tc * 4);
    const float4 cb1 = *reinterpret_cast<const float4*>(catb + 64 + tc * 4);
    const float4 bb0 = *reinterpret_cast<const float4*>(bvec + tc * 4);
    const float4 bb1 = *reinterpret_cast<const float4*>(bvec + 64 + tc * 4);
    #pragma unroll
    for (int rh = 0; rh < 2; ++rh)
        #pragma unroll
        for (int i = 0; i < 4; ++i) {
            int row = r0 + rh * 64 + tr * 4 + i;
            if (row >= n) continue;
            float4 v0 = acc[rh][i][0], v1 = acc[rh][i][1];
            v0.x += cb0.x; v0.y += cb0.y; v0.z += cb0.z; v0.w += cb0.w;
            v1.x += cb1.x; v1.y += cb1.y; v1.z += cb1.z; v1.w += cb1.w;
            float4 r4;
            r4.x = (v0.x > 0.f ? v0.x : ALPHA * v0.x) + bb0.x;
            r4.y = (v0.y > 0.f ? v0.y : ALPHA * v0.y) + bb0.y;
            r4.z = (v0.z > 0.f ? v0.z : ALPHA * v0.z) + bb0.z;
            r4.w = (v0.w > 0.f ? v0.w : ALPHA * v0.w) + bb0.w;
            float4 r5;
            r5.x = (v1.x > 0.f ? v1.x : ALPHA * v1.x) + bb1.x;
            r5.y = (v1.y > 0.f ? v1.y : ALPHA * v1.y) + bb1.y;
            r5.z = (v1.z > 0.f ? v1.z : ALPHA * v1.z) + bb1.z;
            r5.w = (v1.w > 0.f ? v1.w : ALPHA * v1.w) + bb1.w;
            float* dst = out + (size_t)row * EDIM;
            *reinterpret_cast<float4*>(dst + tc * 4) = r4;
            *reinterpret_cast<float4*>(dst + 64 + tc * 4) = r5;
        }
}

// One wave per destination row; lane holds float2 of the 128 output cols.
__global__ void k_spmm_csr(const int* __restrict__ rowptr, const int2* __restrict__ edges,
                           const float* __restrict__ x, float* __restrict__ y, int n) {
    int wid = threadIdx.x >> 6;
    int lane = threadIdx.x & 63;
    int row = blockIdx.x * 4 + wid;
    if (row >= n) return;
    int beg = rowptr[row];
    int end = rowptr[row + 1];
    int c = lane * 2;
    float ax = 0.f, ay = 0.f;
    int j = beg;
    for (; j + 4 <= end; j += 4) {
        int2 e0 = edges[j];
        int2 e1 = edges[j + 1];
        int2 e2 = edges[j + 2];
        int2 e3 = edges[j + 3];
        const float2 x0 = *reinterpret_cast<const float2*>(x + (size_t)e0.x * EDIM + c);
        const float2 x1 = *reinterpret_cast<const float2*>(x + (size_t)e1.x * EDIM + c);
        const float2 x2 = *reinterpret_cast<const float2*>(x + (size_t)e2.x * EDIM + c);
        const float2 x3 = *reinterpret_cast<const float2*>(x + (size_t)e3.x * EDIM + c);
        ax = fmaf(__int_as_float(e0.y), x0.x, ax); ay = fmaf(__int_as_float(e0.y), x0.y, ay);
        ax = fmaf(__int_as_float(e1.y), x1.x, ax); ay = fmaf(__int_as_float(e1.y), x1.y, ay);
        ax = fmaf(__int_as_float(e2.y), x2.x, ax); ay = fmaf(__int_as_float(e2.y), x2.y, ay);
        ax = fmaf(__int_as_float(e3.y), x3.x, ax); ay = fmaf(__int_as_float(e3.y), x3.y, ay);
    }
    for (; j < end; ++j) {
        int2 e = edges[j];
        const float2 xv = *reinterpret_cast<const float2*>(x + (size_t)e.x * EDIM + c);
        ax = fmaf(__int_as_float(e.y), xv.x, ax);
        ay = fmaf(__int_as_float(e.y), xv.y, ay);
    }
    *reinterpret_cast<float2*>(y + (size_t)row * EDIM + c) = make_float2(ax, ay);
}

extern "C" void kernel_launch(void* const* d_in, const int* in_sizes, int n_in,
                              void* d_out, int out_size, void* d_ws, size_t ws_size,
                              hipStream_t stream) {
    const float* feature = (const float*)d_in[0];
    const int*   erow    = (const int*)d_in[1];
    const int*   ecol    = (const int*)d_in[2];
    const float* eval    = (const float*)d_in[3];
    const float* W       = (const float*)d_in[4];
    const float* b       = (const float*)d_in[5];
    const float* catW    = (const float*)d_in[6];
    const float* catb    = (const float*)d_in[7];
    float* out = (float*)d_out;

    const int n  = in_sizes[0] / F_IN;
    const int nE = in_sizes[1];
    const int nb = (n + SCAN_B - 1) / SCAN_B;

    char* p = (char*)d_ws;
    float* support = (float*)p;             p += (size_t)n * EDIM * sizeof(float);
    float* s1      = (float*)p;             p += (size_t)n * EDIM * sizeof(float);
    float* Wt      = (float*)p;             p += (size_t)F_IN * EDIM * sizeof(float);
    int2*  edges   = (int2*)p;              p += (size_t)nE * sizeof(int2);
    int*   cnt     = (int*)p;               p += (size_t)n * sizeof(int);
    int*   rowptr  = (int*)p;               p += (size_t)(n + 1) * sizeof(int);
    int*   cur     = (int*)p;               p += (size_t)n * sizeof(int);
    int*   bsum    = (int*)p;               p += (size_t)nb * sizeof(int);
    int*   boff    = (int*)p;               p += (size_t)(nb + 1) * sizeof(int);

    const int eB = (nE + 255) / 256;
    const int gemmBlocks = (n + BM - 1) / BM;
    const int spmmBlocks = (n + 3) / 4;

    // ---- CSR build ----
    hipMemsetAsync(cnt, 0, (size_t)n * sizeof(int), stream);
    k_hist<<<eB, 256, 0, stream>>>(erow, cnt, nE);
    k_scan_block<<<nb, SCAN_B, 0, stream>>>(cnt, rowptr, bsum, n);
    k_scan_bsums<<<1, SCAN_B, 0, stream>>>(bsum, boff, nb);
    k_add_off<<<nb, SCAN_B, 0, stream>>>(rowptr, cur, boff, n, nb);
    k_scatter<<<eB, 256, 0, stream>>>(erow, ecol, eval, cur, edges, nE);

    // ---- dense prologue ----
    k_transpose_catW<<<(EDIM * 2 * EDIM + 255) / 256, 256, 0, stream>>>(catW, Wt);
    k_gemm1_relu<<<gemmBlocks, 256, 0, stream>>>(feature, W, support, n);

    // ---- SpMMs ----
    k_spmm_csr<<<spmmBlocks, 256, 0, stream>>>(rowptr, edges, support, s1, n);
    k_spmm_csr<<<spmmBlocks, 256, 0, stream>>>(rowptr, edges, s1, out, n);  // s2 -> out

    // ---- epilogue GEMM ----
    k_final<<<gemmBlocks, 256, 0, stream>>>(support, s1, out, Wt, catb, b, n);
}

// Round 4
// 771.878 us; speedup vs baseline: 14.9466x; 1.2583x over previous
//
#include <hip/hip_runtime.h>

#define F_IN 256
#define EDIM 128
#define ALPHA 0.2f
#define SCAN_B 1024
#define BM 128
#define BK 16

typedef unsigned short u16;
typedef unsigned int u32;

__device__ __forceinline__ float b2f(u16 b) {
    union { u32 u; float f; } v; v.u = ((u32)b) << 16; return v.f;
}
__device__ __forceinline__ u16 f2b(float f) {
    union { float f; u32 u; } v; v.f = f;
    u32 r = v.u + 0x7FFFu + ((v.u >> 16) & 1u);
    return (u16)(r >> 16);
}
__device__ __forceinline__ float unpack_lo(u32 g) {
    union { u32 u; float f; } v; v.u = g << 16; return v.f;
}
__device__ __forceinline__ float unpack_hi(u32 g) {
    union { u32 u; float f; } v; v.u = g & 0xFFFF0000u; return v.f;
}

// ---------------- CSR build ----------------

__global__ void k_hist(const int* __restrict__ erow, int* __restrict__ cnt, int nE) {
    int e = blockIdx.x * 256 + threadIdx.x;
    if (e < nE) atomicAdd(&cnt[erow[e]], 1);
}

__global__ void k_scan_block(const int* __restrict__ cnt, int* __restrict__ rp,
                             int* __restrict__ bsum, int n) {
    __shared__ int s[SCAN_B];
    int t = threadIdx.x;
    int i = blockIdx.x * SCAN_B + t;
    int v = (i < n) ? cnt[i] : 0;
    s[t] = v;
    __syncthreads();
    for (int d = 1; d < SCAN_B; d <<= 1) {
        int add = (t >= d) ? s[t - d] : 0;
        __syncthreads();
        s[t] += add;
        __syncthreads();
    }
    if (i < n) rp[i] = s[t] - v;
    if (t == SCAN_B - 1) bsum[blockIdx.x] = s[t];
}

__global__ void k_scan_bsums(const int* __restrict__ bsum, int* __restrict__ boff, int nb) {
    __shared__ int s[SCAN_B];
    int t = threadIdx.x;
    int v = (t < nb) ? bsum[t] : 0;
    s[t] = v;
    __syncthreads();
    for (int d = 1; d < SCAN_B; d <<= 1) {
        int add = (t >= d) ? s[t - d] : 0;
        __syncthreads();
        s[t] += add;
        __syncthreads();
    }
    if (t < nb) boff[t] = s[t] - v;
    if (t == SCAN_B - 1) boff[nb] = s[t];
}

__global__ void k_add_off(int* __restrict__ rp, int* __restrict__ cur,
                          const int* __restrict__ boff, int n, int nb) {
    int i = blockIdx.x * SCAN_B + threadIdx.x;
    if (i < n) {
        int v = rp[i] + boff[blockIdx.x];
        rp[i] = v;
        cur[i] = v;
    }
    if (i == n) rp[n] = boff[nb];
}

__global__ void k_scatter(const int* __restrict__ erow, const int* __restrict__ ecol,
                          const float* __restrict__ eval, int* __restrict__ cur,
                          int2* __restrict__ edges, int nE) {
    int e = blockIdx.x * 256 + threadIdx.x;
    if (e >= nE) return;
    int pos = atomicAdd(&cur[erow[e]], 1);
    edges[pos] = make_int2(ecol[e], __float_as_int(eval[e]));
}

// ---------------- dense ----------------

__global__ void k_transpose_catW(const float* __restrict__ catW, float* __restrict__ Wt) {
    int idx = blockIdx.x * 256 + threadIdx.x;
    if (idx < EDIM * 2 * EDIM) {
        int r = idx >> 8;
        int c = idx & 255;
        Wt[c * EDIM + r] = catW[idx];
    }
}

#define FMA_ROW(accv, a, bv) \
    accv.x = fmaf(a, bv.x, accv.x); accv.y = fmaf(a, bv.y, accv.y); \
    accv.z = fmaf(a, bv.z, accv.z); accv.w = fmaf(a, bv.w, accv.w);

// support(bf16) = relu(feature @ W); 128x128 tile, 256 thr, 8x8 micro-tile.
__global__ __launch_bounds__(256) void k_gemm1_relu(const float* __restrict__ feature,
                                                    const float* __restrict__ W,
                                                    u16* __restrict__ supb, int n) {
    __shared__ float As[BK][BM + 4];
    __shared__ float Bs[BK][EDIM];
    const int t = threadIdx.x;
    const int tr = t >> 4, tc = t & 15;
    const int r0 = blockIdx.x * BM;
    float4 acc[2][4][2];
    #pragma unroll
    for (int rh = 0; rh < 2; ++rh)
        #pragma unroll
        for (int i = 0; i < 4; ++i)
            #pragma unroll
            for (int ch = 0; ch < 2; ++ch)
                acc[rh][i][ch] = make_float4(0.f, 0.f, 0.f, 0.f);

    for (int kt = 0; kt < F_IN / BK; ++kt) {
        const int k0 = kt * BK;
        #pragma unroll
        for (int i = 0; i < 2; ++i) {
            int u = t * 2 + i;
            int r = u >> 2;
            int kc = (u & 3) * 4;
            float4 v = make_float4(0.f, 0.f, 0.f, 0.f);
            if (r0 + r < n)
                v = *reinterpret_cast<const float4*>(feature + (size_t)(r0 + r) * F_IN + k0 + kc);
            As[kc + 0][r] = v.x; As[kc + 1][r] = v.y;
            As[kc + 2][r] = v.z; As[kc + 3][r] = v.w;
        }
        #pragma unroll
        for (int i = 0; i < 2; ++i) {
            int u = t * 2 + i;
            int kb = u >> 5;
            int cb = (u & 31) * 4;
            *reinterpret_cast<float4*>(&Bs[kb][cb]) =
                *reinterpret_cast<const float4*>(W + (size_t)(k0 + kb) * EDIM + cb);
        }
        __syncthreads();
        #pragma unroll
        for (int k = 0; k < BK; ++k) {
            float4 a0 = *reinterpret_cast<const float4*>(&As[k][tr * 4]);
            float4 a1 = *reinterpret_cast<const float4*>(&As[k][64 + tr * 4]);
            float4 b0 = *reinterpret_cast<const float4*>(&Bs[k][tc * 4]);
            float4 b1 = *reinterpret_cast<const float4*>(&Bs[k][64 + tc * 4]);
            FMA_ROW(acc[0][0][0], a0.x, b0) FMA_ROW(acc[0][0][1], a0.x, b1)
            FMA_ROW(acc[0][1][0], a0.y, b0) FMA_ROW(acc[0][1][1], a0.y, b1)
            FMA_ROW(acc[0][2][0], a0.z, b0) FMA_ROW(acc[0][2][1], a0.z, b1)
            FMA_ROW(acc[0][3][0], a0.w, b0) FMA_ROW(acc[0][3][1], a0.w, b1)
            FMA_ROW(acc[1][0][0], a1.x, b0) FMA_ROW(acc[1][0][1], a1.x, b1)
            FMA_ROW(acc[1][1][0], a1.y, b0) FMA_ROW(acc[1][1][1], a1.y, b1)
            FMA_ROW(acc[1][2][0], a1.z, b0) FMA_ROW(acc[1][2][1], a1.z, b1)
            FMA_ROW(acc[1][3][0], a1.w, b0) FMA_ROW(acc[1][3][1], a1.w, b1)
        }
        __syncthreads();
    }
    #pragma unroll
    for (int rh = 0; rh < 2; ++rh)
        #pragma unroll
        for (int i = 0; i < 4; ++i) {
            int row = r0 + rh * 64 + tr * 4 + i;
            if (row >= n) continue;
            u16* dst = supb + (size_t)row * EDIM;
            float4 v0 = acc[rh][i][0], v1 = acc[rh][i][1];
            ushort4 o0, o1;
            o0.x = f2b(fmaxf(v0.x, 0.f)); o0.y = f2b(fmaxf(v0.y, 0.f));
            o0.z = f2b(fmaxf(v0.z, 0.f)); o0.w = f2b(fmaxf(v0.w, 0.f));
            o1.x = f2b(fmaxf(v1.x, 0.f)); o1.y = f2b(fmaxf(v1.y, 0.f));
            o1.z = f2b(fmaxf(v1.z, 0.f)); o1.w = f2b(fmaxf(v1.w, 0.f));
            *reinterpret_cast<ushort4*>(dst + tc * 4) = o0;
            *reinterpret_cast<ushort4*>(dst + 64 + tc * 4) = o1;
        }
}

// y(bf16) = A @ x(bf16): one wave per dest row, lane = 2 cols, f32 accum.
__global__ void k_spmm_csr(const int* __restrict__ rowptr, const int2* __restrict__ edges,
                           const u16* __restrict__ xb, u16* __restrict__ yb, int n) {
    int wid = threadIdx.x >> 6;
    int lane = threadIdx.x & 63;
    int row = blockIdx.x * 4 + wid;
    if (row >= n) return;
    int beg = rowptr[row];
    int end = rowptr[row + 1];
    int c = lane * 2;
    float ax = 0.f, ay = 0.f;
    int j = beg;
    for (; j + 4 <= end; j += 4) {
        int2 e0 = edges[j];
        int2 e1 = edges[j + 1];
        int2 e2 = edges[j + 2];
        int2 e3 = edges[j + 3];
        u32 g0 = *reinterpret_cast<const u32*>(xb + (size_t)e0.x * EDIM + c);
        u32 g1 = *reinterpret_cast<const u32*>(xb + (size_t)e1.x * EDIM + c);
        u32 g2 = *reinterpret_cast<const u32*>(xb + (size_t)e2.x * EDIM + c);
        u32 g3 = *reinterpret_cast<const u32*>(xb + (size_t)e3.x * EDIM + c);
        float v0 = __int_as_float(e0.y), v1 = __int_as_float(e1.y);
        float v2 = __int_as_float(e2.y), v3 = __int_as_float(e3.y);
        ax = fmaf(v0, unpack_lo(g0), ax); ay = fmaf(v0, unpack_hi(g0), ay);
        ax = fmaf(v1, unpack_lo(g1), ax); ay = fmaf(v1, unpack_hi(g1), ay);
        ax = fmaf(v2, unpack_lo(g2), ax); ay = fmaf(v2, unpack_hi(g2), ay);
        ax = fmaf(v3, unpack_lo(g3), ax); ay = fmaf(v3, unpack_hi(g3), ay);
    }
    for (; j < end; ++j) {
        int2 e = edges[j];
        u32 g = *reinterpret_cast<const u32*>(xb + (size_t)e.x * EDIM + c);
        float v = __int_as_float(e.y);
        ax = fmaf(v, unpack_lo(g), ax);
        ay = fmaf(v, unpack_hi(g), ay);
    }
    *reinterpret_cast<u32*>(yb + (size_t)row * EDIM + c) =
        ((u32)f2b(ay) << 16) | (u32)f2b(ax);
}

// out = leaky_relu([s1+sup | s2-sup] @ Wt + catb) + b  (all bf16 inputs, f32 out)
__global__ __launch_bounds__(256) void k_final(const u16* __restrict__ supb,
                                               const u16* __restrict__ s1b,
                                               const u16* __restrict__ s2b,
                                               float* __restrict__ out,
                                               const float* __restrict__ Wt,
                                               const float* __restrict__ catb,
                                               const float* __restrict__ bvec, int n) {
    __shared__ float As[BK][BM + 4];
    __shared__ float Bs[BK][EDIM];
    const int t = threadIdx.x;
    const int tr = t >> 4, tc = t & 15;
    const int r0 = blockIdx.x * BM;
    float4 acc[2][4][2];
    #pragma unroll
    for (int rh = 0; rh < 2; ++rh)
        #pragma unroll
        for (int i = 0; i < 4; ++i)
            #pragma unroll
            for (int ch = 0; ch < 2; ++ch)
                acc[rh][i][ch] = make_float4(0.f, 0.f, 0.f, 0.f);

    for (int kt = 0; kt < (2 * EDIM) / BK; ++kt) {
        const int k0 = kt * BK;
        #pragma unroll
        for (int i = 0; i < 2; ++i) {
            int u = t * 2 + i;
            int r = u >> 2;
            int kc = (u & 3) * 4;
            int kk = k0 + kc;
            float4 v = make_float4(0.f, 0.f, 0.f, 0.f);
            if (r0 + r < n) {
                if (kk < EDIM) {
                    size_t off = (size_t)(r0 + r) * EDIM + kk;
                    ushort4 p = *reinterpret_cast<const ushort4*>(s1b + off);
                    ushort4 q = *reinterpret_cast<const ushort4*>(supb + off);
                    v = make_float4(b2f(p.x) + b2f(q.x), b2f(p.y) + b2f(q.y),
                                    b2f(p.z) + b2f(q.z), b2f(p.w) + b2f(q.w));
                } else {
                    size_t off = (size_t)(r0 + r) * EDIM + (kk - EDIM);
                    ushort4 p = *reinterpret_cast<const ushort4*>(s2b + off);
                    ushort4 q = *reinterpret_cast<const ushort4*>(supb + off);
                    v = make_float4(b2f(p.x) - b2f(q.x), b2f(p.y) - b2f(q.y),
                                    b2f(p.z) - b2f(q.z), b2f(p.w) - b2f(q.w));
                }
            }
            As[kc + 0][r] = v.x; As[kc + 1][r] = v.y;
            As[kc + 2][r] = v.z; As[kc + 3][r] = v.w;
        }
        #pragma unroll
        for (int i = 0; i < 2; ++i) {
            int u = t * 2 + i;
            int kb = u >> 5;
            int cb = (u & 31) * 4;
            *reinterpret_cast<float4*>(&Bs[kb][cb]) =
                *reinterpret_cast<const float4*>(Wt + (size_t)(k0 + kb) * EDIM + cb);
        }
        __syncthreads();
        #pragma unroll
        for (int k = 0; k < BK; ++k) {
            float4 a0 = *reinterpret_cast<const float4*>(&As[k][tr * 4]);
            float4 a1 = *reinterpret_cast<const float4*>(&As[k][64 + tr * 4]);
            float4 b0 = *reinterpret_cast<const float4*>(&Bs[k][tc * 4]);
            float4 b1 = *reinterpret_cast<const float4*>(&Bs[k][64 + tc * 4]);
            FMA_ROW(acc[0][0][0], a0.x, b0) FMA_ROW(acc[0][0][1], a0.x, b1)
            FMA_ROW(acc[0][1][0], a0.y, b0) FMA_ROW(acc[0][1][1], a0.y, b1)
            FMA_ROW(acc[0][2][0], a0.z, b0) FMA_ROW(acc[0][2][1], a0.z, b1)
            FMA_ROW(acc[0][3][0], a0.w, b0) FMA_ROW(acc[0][3][1], a0.w, b1)
            FMA_ROW(acc[1][0][0], a1.x, b0) FMA_ROW(acc[1][0][1], a1.x, b1)
            FMA_ROW(acc[1][1][0], a1.y, b0) FMA_ROW(acc[1][1][1], a1.y, b1)
            FMA_ROW(acc[1][2][0], a1.z, b0) FMA_ROW(acc[1][2][1], a1.z, b1)
            FMA_ROW(acc[1][3][0], a1.w, b0) FMA_ROW(acc[1][3][1], a1.w, b1)
        }
        __syncthreads();
    }
    const float4 cb0 = *reinterpret_cast<const float4*>(catb + tc * 4);
    const float4 cb1 = *reinterpret_cast<const float4*>(catb + 64 + tc * 4);
    const float4 bb0 = *reinterpret_cast<const float4*>(bvec + tc * 4);
    const float4 bb1 = *reinterpret_cast<const float4*>(bvec + 64 + tc * 4);
    #pragma unroll
    for (int rh = 0; rh < 2; ++rh)
        #pragma unroll
        for (int i = 0; i < 4; ++i) {
            int row = r0 + rh * 64 + tr * 4 + i;
            if (row >= n) continue;
            float4 v0 = acc[rh][i][0], v1 = acc[rh][i][1];
            v0.x += cb0.x; v0.y += cb0.y; v0.z += cb0.z; v0.w += cb0.w;
            v1.x += cb1.x; v1.y += cb1.y; v1.z += cb1.z; v1.w += cb1.w;
            float4 r4;
            r4.x = (v0.x > 0.f ? v0.x : ALPHA * v0.x) + bb0.x;
            r4.y = (v0.y > 0.f ? v0.y : ALPHA * v0.y) + bb0.y;
            r4.z = (v0.z > 0.f ? v0.z : ALPHA * v0.z) + bb0.z;
            r4.w = (v0.w > 0.f ? v0.w : ALPHA * v0.w) + bb0.w;
            float4 r5;
            r5.x = (v1.x > 0.f ? v1.x : ALPHA * v1.x) + bb1.x;
            r5.y = (v1.y > 0.f ? v1.y : ALPHA * v1.y) + bb1.y;
            r5.z = (v1.z > 0.f ? v1.z : ALPHA * v1.z) + bb1.z;
            r5.w = (v1.w > 0.f ? v1.w : ALPHA * v1.w) + bb1.w;
            float* dst = out + (size_t)row * EDIM;
            *reinterpret_cast<float4*>(dst + tc * 4) = r4;
            *reinterpret_cast<float4*>(dst + 64 + tc * 4) = r5;
        }
}

extern "C" void kernel_launch(void* const* d_in, const int* in_sizes, int n_in,
                              void* d_out, int out_size, void* d_ws, size_t ws_size,
                              hipStream_t stream) {
    const float* feature = (const float*)d_in[0];
    const int*   erow    = (const int*)d_in[1];
    const int*   ecol    = (const int*)d_in[2];
    const float* eval    = (const float*)d_in[3];
    const float* W       = (const float*)d_in[4];
    const float* b       = (const float*)d_in[5];
    const float* catW    = (const float*)d_in[6];
    const float* catb    = (const float*)d_in[7];
    float* out = (float*)d_out;

    const int n  = in_sizes[0] / F_IN;
    const int nE = in_sizes[1];
    const int nb = (n + SCAN_B - 1) / SCAN_B;

    char* p = (char*)d_ws;
    u16*  supb = (u16*)p;                   p += (size_t)n * EDIM * sizeof(u16);
    u16*  s1b  = (u16*)p;                   p += (size_t)n * EDIM * sizeof(u16);
    u16*  s2b  = (u16*)p;                   p += (size_t)n * EDIM * sizeof(u16);
    p = (char*)(((size_t)p + 15) & ~(size_t)15);
    float* Wt  = (float*)p;                 p += (size_t)F_IN * EDIM * sizeof(float);
    int2* edges = (int2*)p;                 p += (size_t)nE * sizeof(int2);
    int*  cnt   = (int*)p;                  p += (size_t)n * sizeof(int);
    int*  rowptr = (int*)p;                 p += (size_t)(n + 1) * sizeof(int);
    int*  cur    = (int*)p;                 p += (size_t)n * sizeof(int);
    int*  bsum   = (int*)p;                 p += (size_t)nb * sizeof(int);
    int*  boff   = (int*)p;                 p += (size_t)(nb + 1) * sizeof(int);

    const int eB = (nE + 255) / 256;
    const int gemmBlocks = (n + BM - 1) / BM;
    const int spmmBlocks = (n + 3) / 4;

    // ---- CSR build ----
    hipMemsetAsync(cnt, 0, (size_t)n * sizeof(int), stream);
    k_hist<<<eB, 256, 0, stream>>>(erow, cnt, nE);
    k_scan_block<<<nb, SCAN_B, 0, stream>>>(cnt, rowptr, bsum, n);
    k_scan_bsums<<<1, SCAN_B, 0, stream>>>(bsum, boff, nb);
    k_add_off<<<nb, SCAN_B, 0, stream>>>(rowptr, cur, boff, n, nb);
    k_scatter<<<eB, 256, 0, stream>>>(erow, ecol, eval, cur, edges, nE);

    // ---- dense prologue ----
    k_transpose_catW<<<(EDIM * 2 * EDIM + 255) / 256, 256, 0, stream>>>(catW, Wt);
    k_gemm1_relu<<<gemmBlocks, 256, 0, stream>>>(feature, W, supb, n);

    // ---- SpMMs (bf16 gather, f32 accum) ----
    k_spmm_csr<<<spmmBlocks, 256, 0, stream>>>(rowptr, edges, supb, s1b, n);
    k_spmm_csr<<<spmmBlocks, 256, 0, stream>>>(rowptr, edges, s1b, s2b, n);

    // ---- epilogue GEMM ----
    k_final<<<gemmBlocks, 256, 0, stream>>>(supb, s1b, s2b, out, Wt, catb, b, n);
}